// Round 5
// baseline (678.319 us; speedup 1.0000x reference)
//
#include <hip/hip_runtime.h>
#include <hip/hip_cooperative_groups.h>
#include <stdint.h>
#include <math.h>

namespace cg = cooperative_groups;

// ---------------------------------------------------------------------------
// XNOR-Net forward, single cooperative kernel.
// R1-R4 showed per-kernel compute is ~25-35us total but 8 dependent launches
// cost ~150us (launch/serialization gaps; harness fills crowd the profile).
// R5: one hipLaunchCooperativeKernel with 5 grid.sync()s. Per-element math is
// byte-identical to R4 (exact integer popcount dots, f64 epilogues, same
// summation orders) -> absmax must stay 0.0.
// ---------------------------------------------------------------------------

// ws layout (bytes)
#define A_OFF      0ull        // double[4]        alphas
#define WM1_OFF    1024ull     // uint32[64]       layer1 weight sign masks
#define WP2_OFF    2048ull     // u64[128*9]       layer2 packed weights [co][tap]
#define WP3T_OFF   16384ull    // u64[18*256]      layer3 packed weights [tap*2+half][co]
#define WFP_OFF    65536ull    // u64[1000*4]      fc packed weights
#define PART_OFF   100352ull   // double[128]      alpha partial sums
#define P1_OFF     102400ull   // u64[32*112*112]  layer1 out signs (bit=co)
#define P2_OFF     3313664ull  // u32[32*56*56*4]  layer2 out signs (quarters)
#define POOLP_OFF  4919296ull  // double[32*28*256] conv3 row-partial pool sums

__global__ __launch_bounds__(256, 4) void k_fused(
    const float* __restrict__ x,  const float* __restrict__ w1, const float* __restrict__ b1,
    const float* __restrict__ w2, const float* __restrict__ b2,
    const float* __restrict__ w3, const float* __restrict__ b3,
    const float* __restrict__ wf, const float* __restrict__ bf,
    double* alphas, double* part, uint32_t* wm1, uint64_t* wp2,
    uint64_t* wp3t, uint64_t* wfp, uint64_t* p1, uint32_t* p2,
    double* poolp, float* out)
{
    cg::grid_group grid = cg::this_grid();
    __shared__ uint64_t smem[1152];            // 9216 B, unioned across stages
    const int tid  = threadIdx.x;
    const int lane = tid & 63;
    const int bid  = blockIdx.x;
    const int nblk = gridDim.x;
    const int gw   = bid * 4 + (tid >> 6);     // global wave id
    const int nw   = nblk * 4;

    // ================= Stage A: weight pack + alpha partials =================
    for (int w = gw; w < 1152; w += nw) {      // wp2: word = co*9+tap, lane=ci
        int co = w / 9, tap = w % 9, kh = tap / 3, kw = tap % 3;
        uint64_t b = __ballot(w2[((co*64 + lane)*3 + kh)*3 + kw] >= 0.f);
        if (lane == 0) wp2[w] = b;
    }
    for (int w = gw; w < 4608; w += nw) {      // wp3t: word = co*18 + tap*2+half
        int co = w / 18, r = w % 18, tap = r / 2, half = r & 1;
        int kh = tap / 3, kw = tap % 3;
        uint64_t b = __ballot(w3[((co*128 + half*64 + lane)*3 + kh)*3 + kw] >= 0.f);
        if (lane == 0) wp3t[(tap*2 + half)*256 + co] = b;
    }
    for (int w = gw; w < 4000; w += nw) {      // wfp: word = o*4+j
        int o = w >> 2, j = w & 3;
        uint64_t b = __ballot(wf[o*256 + j*64 + lane] >= 0.f);
        if (lane == 0) wfp[w] = b;
    }
    if (bid == nblk - 1 && tid < 64) {         // wm1 (27-bit masks)
        uint32_t m = 0;
        for (int t = 0; t < 27; t++) {
            int ci = t / 9, r = t % 9, kh = r / 3, kw = r % 3;
            if (w1[((tid*3 + ci)*3 + kh)*3 + kw] >= 0.f) m |= (1u << t);
        }
        wm1[tid] = m;
    }
    if (bid < 128) {                           // alpha partials (same as R4)
        double* sd = (double*)smem;
        int t = bid >> 5, c = bid & 31;
        const float* w; int n;
        if (t == 0)      { w = w1; n = 64*3*9; }
        else if (t == 1) { w = w2; n = 128*64*9; }
        else if (t == 2) { w = w3; n = 256*128*9; }
        else             { w = wf; n = 1000*256; }
        int per = (n + 31) / 32;
        int lo = c * per, hi = min(n, lo + per);
        double s0 = 0.0, s1 = 0.0, s2 = 0.0, s3 = 0.0;
        int i = lo + tid;
        for (; i + 768 < hi; i += 1024) {
            s0 += fabs((double)w[i]);
            s1 += fabs((double)w[i + 256]);
            s2 += fabs((double)w[i + 512]);
            s3 += fabs((double)w[i + 768]);
        }
        for (; i < hi; i += 256) s0 += fabs((double)w[i]);
        sd[tid] = (s0 + s1) + (s2 + s3);
        __syncthreads();
        for (int off = 128; off > 0; off >>= 1) {
            if (tid < off) sd[tid] += sd[tid + off];
            __syncthreads();
        }
        if (tid == 0) part[bid] = sd[0];
    }
    __threadfence();
    grid.sync();

    // ================= Stage B: alpha finalize (serial order = R4) ===========
    if (bid == 0 && tid < 4) {
        const int ns[4] = {64*3*9, 128*64*9, 256*128*9, 1000*256};
        double s = 0.0;
        for (int j = 0; j < 32; j++) s += part[tid*32 + j];
        alphas[tid] = s / (double)ns[tid];
    }
    __threadfence();
    grid.sync();

    // ================= Stage C: conv1 -> p1 =================================
    {
        uint32_t* wm = (uint32_t*)smem;
        if (tid < 64) wm[tid] = wm1[tid];
        __syncthreads();
        double a = alphas[0]; double a2 = a * a;
        for (int vb = bid; vb < 1568; vb += nblk) {
            int idx = vb * 256 + tid;
            int wo = idx % 112, t1 = idx / 112;
            int ho = t1 % 112, n = t1 / 112;
            uint32_t xm = 0, vm = 0;
            #pragma unroll
            for (int ci = 0; ci < 3; ci++)
                #pragma unroll
                for (int kh = 0; kh < 3; kh++) {
                    int hi = 2*ho + kh - 1;
                    if ((unsigned)hi >= 224u) continue;
                    #pragma unroll
                    for (int kw = 0; kw < 3; kw++) {
                        int wi = 2*wo + kw - 1;
                        if ((unsigned)wi >= 224u) continue;
                        int t = ci*9 + kh*3 + kw;
                        vm |= (1u << t);
                        if (x[((n*3 + ci)*224 + hi)*224 + wi] >= 0.f) xm |= (1u << t);
                    }
                }
            int V = __popc(vm);
            uint64_t bits = 0;
            for (int co = 0; co < 64; co++) {
                int m = __popc((~(xm ^ wm[co])) & vm);
                double h = a2 * (double)(2*m - V) + (double)b1[co];
                if (h >= 0.0) bits |= (1ull << co);
            }
            p1[idx] = bits;
        }
    }
    __threadfence();
    grid.sync();

    // ================= Stage D: conv2 -> p2 =================================
    {
        for (int i = tid; i < 1152; i += 256) smem[i] = wp2[i];
        __syncthreads();
        double a = alphas[1]; double a2 = a * a;
        int q = tid >> 6;
        int co0 = q * 32;
        for (int vb = bid; vb < 1568; vb += nblk) {
            int pos = vb * 64 + lane;
            int wo = pos % 56, t1 = pos / 56;
            int ho = t1 % 56, n = t1 / 56;
            uint64_t xv[9]; uint64_t vmask[9]; int V = 0;
            #pragma unroll
            for (int kh = 0; kh < 3; kh++)
                #pragma unroll
                for (int kw = 0; kw < 3; kw++) {
                    int t = kh*3 + kw;
                    int hi = 2*ho + kh - 1, wi = 2*wo + kw - 1;
                    bool ok = ((unsigned)hi < 112u) && ((unsigned)wi < 112u);
                    vmask[t] = ok ? ~0ull : 0ull;
                    xv[t] = ok ? p1[(n*112 + hi)*112 + wi] : 0ull;
                    V += ok ? 1 : 0;
                }
            int base = 64 * V;
            uint32_t bits = 0;
            for (int c = 0; c < 32; c++) {
                int co = co0 + c;
                int m = 0;
                #pragma unroll
                for (int t = 0; t < 9; t++)
                    m += __popcll((xv[t] ^ smem[co*9 + t]) & vmask[t]);
                double h = a2 * (double)(base - 2*m) + (double)b2[co];
                if (h >= 0.0) bits |= (1u << c);
            }
            p2[pos*4 + q] = bits;
        }
    }
    __threadfence();
    grid.sync();

    // ================= Stage E: conv3 + pool row partials ===================
    {
        uint64_t w[18];
        #pragma unroll
        for (int i = 0; i < 18; i++) w[i] = wp3t[i*256 + tid];
        uint32_t P[9];
        #pragma unroll
        for (int t = 0; t < 9; t++) P[t] = __popcll(w[2*t]) + __popcll(w[2*t+1]);
        double a = alphas[2]; double a2 = a * a;
        double bc = (double)b3[tid];
        for (int vb = bid; vb < 896; vb += nblk) {
            int n = vb / 28, ho = vb % 28;
            __syncthreads();                  // protect smem reuse across iters
            for (int i = tid; i < 504; i += 256) {
                int wo = i / 18, r = i % 18;
                int tap = r / 2, half = r % 2;
                int kh = tap / 3, kw = tap % 3;
                int hi = 2*ho + kh - 1, wi = 2*wo + kw - 1;
                bool ok = ((unsigned)hi < 56u) && ((unsigned)wi < 56u);
                smem[i] = ok ? ((const uint64_t*)p2)[(size_t)((n*56 + hi)*56 + wi)*2 + half] : 0ull;
            }
            __syncthreads();
            bool htop = (ho == 0);
            int rv = htop ? 2 : 3;
            double sum = 0.0;
            for (int wo = 0; wo < 28; wo++) {
                int mm = 0;
                #pragma unroll
                for (int t = 0; t < 18; t++)
                    mm += __popcll(smem[wo*18 + t] ^ w[t]);
                bool wl = (wo == 0);
                int cv = wl ? 2 : 3;
                int corr = 0;
                if (htop) corr += P[0] + P[1] + P[2];
                if (wl)   corr += P[0] + P[3] + P[6];
                if (htop && wl) corr -= P[0];
                int dot = 128*(rv*cv) - 2*mm + 2*corr;
                double h = a2 * (double)dot + bc;
                h = fmin(fmax(h, -1.0), 1.0);
                sum += h;
            }
            poolp[(size_t)(n*28 + ho)*256 + tid] = sum;
        }
    }
    __threadfence();
    grid.sync();

    // ================= Stage F: pool finalize + FC (block n) ================
    if (bid < 32) {
        int n = bid;
        double s = 0.0;
        for (int c = 0; c < 28; c++) s += poolp[(size_t)(n*28 + c)*256 + tid];
        uint64_t bal = __ballot((s / 784.0) >= 0.0);
        uint64_t* spl = smem;
        if (lane == 0) spl[tid >> 6] = bal;
        __syncthreads();
        uint64_t s0 = spl[0], s1 = spl[1], s2 = spl[2], s3 = spl[3];
        double a = alphas[3]; double aa = a * a;
        for (int o = tid; o < 1000; o += 256) {
            int m = __popcll(s0 ^ wfp[o*4]) + __popcll(s1 ^ wfp[o*4+1])
                  + __popcll(s2 ^ wfp[o*4+2]) + __popcll(s3 ^ wfp[o*4+3]);
            out[n*1000 + o] = (float)(aa * (double)(256 - 2*m) + (double)bf[o]);
        }
    }
}

extern "C" void kernel_launch(void* const* d_in, const int* in_sizes, int n_in,
                              void* d_out, int out_size, void* d_ws, size_t ws_size,
                              hipStream_t stream) {
    const float* x  = (const float*)d_in[0];
    const float* w1 = (const float*)d_in[1];
    const float* b1 = (const float*)d_in[2];
    const float* w2 = (const float*)d_in[3];
    const float* b2 = (const float*)d_in[4];
    const float* w3 = (const float*)d_in[5];
    const float* b3 = (const float*)d_in[6];
    const float* wf = (const float*)d_in[7];
    const float* bf = (const float*)d_in[8];

    char* ws = (char*)d_ws;
    double*   alphas = (double*)  (ws + A_OFF);
    uint32_t* wm1    = (uint32_t*)(ws + WM1_OFF);
    uint64_t* wp2    = (uint64_t*)(ws + WP2_OFF);
    uint64_t* wp3t   = (uint64_t*)(ws + WP3T_OFF);
    uint64_t* wfp    = (uint64_t*)(ws + WFP_OFF);
    double*   part   = (double*)  (ws + PART_OFF);
    uint64_t* p1     = (uint64_t*)(ws + P1_OFF);
    uint32_t* p2     = (uint32_t*)(ws + P2_OFF);
    double*   poolp  = (double*)  (ws + POOLP_OFF);
    float*    outp   = (float*)   d_out;

    void* args[] = {
        (void*)&x, (void*)&w1, (void*)&b1, (void*)&w2, (void*)&b2,
        (void*)&w3, (void*)&b3, (void*)&wf, (void*)&bf,
        (void*)&alphas, (void*)&part, (void*)&wm1, (void*)&wp2,
        (void*)&wp3t, (void*)&wfp, (void*)&p1, (void*)&p2,
        (void*)&poolp, (void*)&outp
    };
    hipLaunchCooperativeKernel((const void*)k_fused, dim3(512), dim3(256),
                               args, 0, stream);
}

// Round 6
// 150.956 us; speedup vs baseline: 4.4935x; 4.4935x over previous
//
#include <hip/hip_runtime.h>
#include <stdint.h>
#include <math.h>

// ---------------------------------------------------------------------------
// XNOR-Net forward: 3 binarized stride-2 convs + global avg pool + binary FC.
// Exact integer popcount dots + f64 epilogues (absmax 0.0 in R1/R2/R4).
// R5 post-mortem: cooperative grid.sync costs ~100us each on 8-XCD MI355X
// (device-scope L2 coherence) -> 678us. Reverted to stream-ordered kernels.
// R6: 4 launches instead of R4's 8:
//   K1 = conv1 (self-packs wm1 + alpha1 per block) + extra blocks packing
//        wp2/wp3t/wfp and alpha2/3/4 partials (disjoint data, same dispatch)
//   K2 = conv2 (finalizes alpha2 from part[], bitwise-identical serial sum)
//   K3 = conv3+pool row partials (finalizes alpha3)
//   K4 = pool finalize + FC per image (finalizes alpha4)
// ---------------------------------------------------------------------------

// ws layout (bytes)
#define A_OFF      0ull        // (unused spare)
#define WP2_OFF    2048ull     // u64[128*9]       layer2 packed weights [co][tap]
#define WP3T_OFF   16384ull    // u64[18*256]      layer3 packed weights [tap*2+half][co]
#define WFP_OFF    65536ull    // u64[1000*4]      fc packed weights
#define PART_OFF   100352ull   // double[128]      alpha partials (t=1:w2, t=2:w3, t=3:wf)
#define P1_OFF     102400ull   // u64[32*112*112]  layer1 out signs (bit=co)
#define P2_OFF     3313664ull  // u32[32*56*56*4]  layer2 out signs (quarters)
#define POOLP_OFF  4919296ull  // double[32*28*256] conv3 row-partial pool sums

// ---- K1: conv1 (blocks 0..1567) + weight pack / alpha partials (1568..1727)
__global__ __launch_bounds__(256) void k1_conv1_pack(
    const float* __restrict__ x,  const float* __restrict__ w1, const float* __restrict__ b1,
    const float* __restrict__ w2, const float* __restrict__ w3, const float* __restrict__ wf,
    uint64_t* __restrict__ wp2, uint64_t* __restrict__ wp3t, uint64_t* __restrict__ wfp,
    double* __restrict__ part, uint64_t* __restrict__ p1)
{
    const int tid = threadIdx.x, lane = tid & 63, bid = blockIdx.x;
    if (bid < 1568) {
        __shared__ double sd[256];
        __shared__ uint32_t wm[64];
        // per-block alpha1 (w1 is 1728 floats; deterministic, identical in all blocks)
        double s = 0.0;
        for (int i = tid; i < 1728; i += 256) s += fabs((double)w1[i]);
        sd[tid] = s;
        // per-block wm1 pack
        if (tid < 64) {
            uint32_t m = 0;
            for (int t = 0; t < 27; t++) {
                int ci = t / 9, r = t % 9, kh = r / 3, kw = r % 3;
                if (w1[((tid*3 + ci)*3 + kh)*3 + kw] >= 0.f) m |= (1u << t);
            }
            wm[tid] = m;
        }
        __syncthreads();
        for (int off = 128; off > 0; off >>= 1) {
            if (tid < off) sd[tid] += sd[tid + off];
            __syncthreads();
        }
        double a = sd[0] / 1728.0;
        double a2 = a * a;

        int idx = bid * 256 + tid;
        int wo = idx % 112, t1 = idx / 112;
        int ho = t1 % 112, n = t1 / 112;
        uint32_t xm = 0, vm = 0;
        #pragma unroll
        for (int ci = 0; ci < 3; ci++)
            #pragma unroll
            for (int kh = 0; kh < 3; kh++) {
                int hi = 2*ho + kh - 1;
                if ((unsigned)hi >= 224u) continue;
                #pragma unroll
                for (int kw = 0; kw < 3; kw++) {
                    int wi = 2*wo + kw - 1;
                    if ((unsigned)wi >= 224u) continue;
                    int t = ci*9 + kh*3 + kw;
                    vm |= (1u << t);
                    if (x[((n*3 + ci)*224 + hi)*224 + wi] >= 0.f) xm |= (1u << t);
                }
            }
        int V = __popc(vm);
        uint64_t bits = 0;
        for (int co = 0; co < 64; co++) {
            int m = __popc((~(xm ^ wm[co])) & vm);
            double h = a2 * (double)(2*m - V) + (double)b1[co];
            if (h >= 0.0) bits |= (1ull << co);
        }
        p1[idx] = bits;
    } else {
        int rel = bid - 1568;                 // 0..159
        // alpha partials, R4-identical chunk pattern (t: 0->w2,1->w3,2->wf)
        if (rel < 96) {
            __shared__ double sd[256];
            int t = rel >> 5, c = rel & 31;
            const float* w; int n;
            if (t == 0)      { w = w2; n = 128*64*9; }
            else if (t == 1) { w = w3; n = 256*128*9; }
            else             { w = wf; n = 1000*256; }
            int per = (n + 31) / 32;
            int lo = c * per, hi = min(n, lo + per);
            double s0 = 0.0, s1 = 0.0, s2 = 0.0, s3 = 0.0;
            int i = lo + tid;
            for (; i + 768 < hi; i += 1024) {
                s0 += fabs((double)w[i]);
                s1 += fabs((double)w[i + 256]);
                s2 += fabs((double)w[i + 512]);
                s3 += fabs((double)w[i + 768]);
            }
            for (; i < hi; i += 256) s0 += fabs((double)w[i]);
            sd[tid] = (s0 + s1) + (s2 + s3);
            __syncthreads();
            for (int off = 128; off > 0; off >>= 1) {
                if (tid < off) sd[tid] += sd[tid + off];
                __syncthreads();
            }
            if (tid == 0) part[(t + 1)*32 + c] = sd[0];
        }
        // ballot packing, distributed across all 160 pack blocks (640 waves)
        int gw = rel * 4 + (tid >> 6);
        const int nw = 640;
        for (int w = gw; w < 1152; w += nw) {   // wp2: word = co*9+tap, lane=ci
            int co = w / 9, tap = w % 9, kh = tap / 3, kw = tap % 3;
            uint64_t b = __ballot(w2[((co*64 + lane)*3 + kh)*3 + kw] >= 0.f);
            if (lane == 0) wp2[w] = b;
        }
        for (int w = gw; w < 4608; w += nw) {   // wp3t: [tap*2+half][co]
            int co = w / 18, r = w % 18, tap = r / 2, half = r & 1;
            int kh = tap / 3, kw = tap % 3;
            uint64_t b = __ballot(w3[((co*128 + half*64 + lane)*3 + kh)*3 + kw] >= 0.f);
            if (lane == 0) wp3t[(tap*2 + half)*256 + co] = b;
        }
        for (int w = gw; w < 4000; w += nw) {   // wfp: word = o*4+j
            int o = w >> 2, j = w & 3;
            uint64_t b = __ballot(wf[o*256 + j*64 + lane] >= 0.f);
            if (lane == 0) wfp[w] = b;
        }
    }
}

// ---- K2: conv2. alpha2 finalized in-kernel (serial sum = R4's alpha_fin). ----
__global__ __launch_bounds__(256) void k2_conv2(
    const uint64_t* __restrict__ p1, const float* __restrict__ b2,
    const double* __restrict__ part, const uint64_t* __restrict__ wp2g,
    uint32_t* __restrict__ p2)
{
    __shared__ uint64_t wp[1152];
    const int tid = threadIdx.x, lane = tid & 63;
    for (int i = tid; i < 1152; i += 256) wp[i] = wp2g[i];
    double s = 0.0;
    for (int j = 0; j < 32; j++) s += part[32 + j];
    double a = s / (double)(128*64*9);
    double a2 = a * a;
    __syncthreads();
    int q = tid >> 6;
    int co0 = q * 32;
    int pos = blockIdx.x * 64 + lane;
    int wo = pos % 56, t1 = pos / 56;
    int ho = t1 % 56, n = t1 / 56;
    uint64_t xv[9]; uint64_t vmask[9]; int V = 0;
    #pragma unroll
    for (int kh = 0; kh < 3; kh++)
        #pragma unroll
        for (int kw = 0; kw < 3; kw++) {
            int t = kh*3 + kw;
            int hi = 2*ho + kh - 1, wi = 2*wo + kw - 1;
            bool ok = ((unsigned)hi < 112u) && ((unsigned)wi < 112u);
            vmask[t] = ok ? ~0ull : 0ull;
            xv[t] = ok ? p1[(n*112 + hi)*112 + wi] : 0ull;
            V += ok ? 1 : 0;
        }
    int base = 64 * V;
    uint32_t bits = 0;
    for (int c = 0; c < 32; c++) {
        int co = co0 + c;
        int m = 0;
        #pragma unroll
        for (int t = 0; t < 9; t++)
            m += __popcll((xv[t] ^ wp[co*9 + t]) & vmask[t]);
        double h = a2 * (double)(base - 2*m) + (double)b2[co];
        if (h >= 0.0) bits |= (1u << c);
    }
    p2[pos*4 + q] = bits;
}

// ---- K3: conv3 + pool row partials. block=(n,ho), thread=co. ----
// Only ho==0 / wo==0 are borders (even input 56, stride 2, pad 1).
__global__ __launch_bounds__(256) void k3_conv3pool(
    const uint64_t* __restrict__ p2, const float* __restrict__ b3,
    const double* __restrict__ part, const uint64_t* __restrict__ wp3t,
    double* __restrict__ partial)
{
    __shared__ uint64_t xs[28*18];
    const int tid = threadIdx.x;
    int n = blockIdx.x / 28, ho = blockIdx.x % 28;

    double s = 0.0;
    for (int j = 0; j < 32; j++) s += part[64 + j];
    double a = s / (double)(256*128*9);
    double a2 = a * a;

    uint64_t w[18];
    #pragma unroll
    for (int i = 0; i < 18; i++) w[i] = wp3t[i*256 + tid];
    uint32_t P[9];
    #pragma unroll
    for (int t = 0; t < 9; t++) P[t] = __popcll(w[2*t]) + __popcll(w[2*t+1]);

    for (int i = tid; i < 504; i += 256) {
        int wo = i / 18, r = i % 18;
        int tap = r / 2, half = r % 2;
        int kh = tap / 3, kw = tap % 3;
        int hi = 2*ho + kh - 1, wi = 2*wo + kw - 1;
        bool ok = ((unsigned)hi < 56u) && ((unsigned)wi < 56u);
        xs[i] = ok ? p2[(size_t)((n*56 + hi)*56 + wi)*2 + half] : 0ull;
    }
    __syncthreads();

    bool htop = (ho == 0);
    int rv = htop ? 2 : 3;
    double bc = (double)b3[tid];
    double sum = 0.0;
    for (int wo = 0; wo < 28; wo++) {
        int mm = 0;
        #pragma unroll
        for (int t = 0; t < 18; t++)
            mm += __popcll(xs[wo*18 + t] ^ w[t]);
        bool wl = (wo == 0);
        int cv = wl ? 2 : 3;
        int corr = 0;
        if (htop) corr += P[0] + P[1] + P[2];
        if (wl)   corr += P[0] + P[3] + P[6];
        if (htop && wl) corr -= P[0];
        int dot = 128*(rv*cv) - 2*mm + 2*corr;
        double h = a2 * (double)dot + bc;
        h = fmin(fmax(h, -1.0), 1.0);
        sum += h;
    }
    partial[(size_t)(n*28 + ho)*256 + tid] = sum;
}

// ---- K4: pool finalize (ho-order sum) + FC, block = image n ----
__global__ __launch_bounds__(256) void k4_poolfc(
    const double* __restrict__ partial, const uint64_t* __restrict__ wfp,
    const float* __restrict__ bf, const double* __restrict__ part,
    float* __restrict__ out)
{
    __shared__ uint64_t spl[4];
    const int tid = threadIdx.x, lane = tid & 63;
    int n = blockIdx.x;
    double s = 0.0;
    for (int c = 0; c < 28; c++) s += partial[(size_t)(n*28 + c)*256 + tid];
    uint64_t bal = __ballot((s / 784.0) >= 0.0);
    if (lane == 0) spl[tid >> 6] = bal;

    double sa = 0.0;
    for (int j = 0; j < 32; j++) sa += part[96 + j];
    double a = sa / (double)(1000*256);
    double aa = a * a;
    __syncthreads();
    uint64_t s0 = spl[0], s1 = spl[1], s2 = spl[2], s3 = spl[3];
    for (int o = tid; o < 1000; o += 256) {
        int m = __popcll(s0 ^ wfp[o*4]) + __popcll(s1 ^ wfp[o*4+1])
              + __popcll(s2 ^ wfp[o*4+2]) + __popcll(s3 ^ wfp[o*4+3]);
        out[n*1000 + o] = (float)(aa * (double)(256 - 2*m) + (double)bf[o]);
    }
}

extern "C" void kernel_launch(void* const* d_in, const int* in_sizes, int n_in,
                              void* d_out, int out_size, void* d_ws, size_t ws_size,
                              hipStream_t stream) {
    const float* x  = (const float*)d_in[0];
    const float* w1 = (const float*)d_in[1];
    const float* b1 = (const float*)d_in[2];
    const float* w2 = (const float*)d_in[3];
    const float* b2 = (const float*)d_in[4];
    const float* w3 = (const float*)d_in[5];
    const float* b3 = (const float*)d_in[6];
    const float* wf = (const float*)d_in[7];
    const float* bf = (const float*)d_in[8];

    char* ws = (char*)d_ws;
    uint64_t* wp2    = (uint64_t*)(ws + WP2_OFF);
    uint64_t* wp3t   = (uint64_t*)(ws + WP3T_OFF);
    uint64_t* wfp    = (uint64_t*)(ws + WFP_OFF);
    double*   part   = (double*)  (ws + PART_OFF);
    uint64_t* p1     = (uint64_t*)(ws + P1_OFF);
    uint32_t* p2     = (uint32_t*)(ws + P2_OFF);
    double*   poolp  = (double*)  (ws + POOLP_OFF);
    float*    out    = (float*)   d_out;

    hipLaunchKernelGGL(k1_conv1_pack, dim3(1728), dim3(256), 0, stream,
                       x, w1, b1, w2, w3, wf, wp2, wp3t, wfp, part, p1);
    hipLaunchKernelGGL(k2_conv2,      dim3(1568), dim3(256), 0, stream,
                       p1, b2, part, wp2, p2);
    hipLaunchKernelGGL(k3_conv3pool,  dim3(896),  dim3(256), 0, stream,
                       (const uint64_t*)p2, b3, part, wp3t, poolp);
    hipLaunchKernelGGL(k4_poolfc,     dim3(32),   dim3(256), 0, stream,
                       poolp, wfp, bf, part, out);
}

// Round 7
// 146.076 us; speedup vs baseline: 4.6436x; 1.0334x over previous
//
#include <hip/hip_runtime.h>
#include <stdint.h>
#include <math.h>

// ---------------------------------------------------------------------------
// XNOR-Net forward: 3 binarized stride-2 convs + global avg pool + binary FC.
// Exact integer popcount dots + f64 epilogues (absmax 0.0 R1/R2/R4/R6).
// Budget (R5/R6 evidence): ~85us fixed harness work (268MB ws poison fill,
// restores) + our kernels. Launch gap ~2us (R4->R6: 8->4 launches = -6us).
// R7: (a) K1 alpha1 via single-wave butterfly (was: all-thread 8-barrier
// tree per block, ~doubling K1); (b) K2 maskless inner loop (xor+popc only)
// with exact border-correction table dtab[co][cfg] = 64V+2corr, activations
// staged zero-padded in LDS [tap][pos] (conflict-free, 4x fewer p1 reads).
// dot integers remain bit-identical to R6's masked form.
// ---------------------------------------------------------------------------

// ws layout (bytes)
#define WP2_OFF    2048ull     // u64[128*9]       layer2 packed weights [co][tap]
#define WP3T_OFF   16384ull    // u64[18*256]      layer3 packed weights [tap*2+half][co]
#define WFP_OFF    65536ull    // u64[1000*4]      fc packed weights
#define PART_OFF   100352ull   // double[128]      alpha partials (t=1:w2,2:w3,3:wf)
#define P1_OFF     102400ull   // u64[32*112*112]  layer1 out signs (bit=co)
#define P2_OFF     3313664ull  // u32[32*56*56*4]  layer2 out signs (quarters)
#define POOLP_OFF  4919296ull  // double[32*28*256] conv3 row-partial pool sums

// ---- K1: conv1 (blocks 0..1567) + weight pack / alpha partials (1568..1727)
__global__ __launch_bounds__(256) void k1_conv1_pack(
    const float* __restrict__ x,  const float* __restrict__ w1, const float* __restrict__ b1,
    const float* __restrict__ w2, const float* __restrict__ w3, const float* __restrict__ wf,
    uint64_t* __restrict__ wp2, uint64_t* __restrict__ wp3t, uint64_t* __restrict__ wfp,
    double* __restrict__ part, uint64_t* __restrict__ p1)
{
    const int tid = threadIdx.x, lane = tid & 63, wid = tid >> 6, bid = blockIdx.x;
    if (bid < 1568) {
        __shared__ double a2s;
        __shared__ double db1[64];
        __shared__ uint32_t wm[64];
        // wave 0: alpha1 (27 coalesced loads/lane + butterfly; deterministic,
        // identical in every block)
        if (wid == 0) {
            double s = 0.0;
            #pragma unroll
            for (int i = 0; i < 27; i++) s += fabs((double)w1[lane + i*64]);
            #pragma unroll
            for (int off = 1; off < 64; off <<= 1) s += __shfl_xor(s, off, 64);
            if (lane == 0) { double a = s / 1728.0; a2s = a * a; }
        } else if (wid == 1) {          // wave 1: wm1 pack
            uint32_t m = 0;
            for (int t = 0; t < 27; t++) {
                int ci = t / 9, r = t % 9, kh = r / 3, kw = r % 3;
                if (w1[((lane*3 + ci)*3 + kh)*3 + kw] >= 0.f) m |= (1u << t);
            }
            wm[lane] = m;
        } else if (wid == 2) {          // wave 2: bias -> f64
            db1[lane] = (double)b1[lane];
        }
        // all threads: gather 27 sign taps (long-latency loads overlap setup)
        int idx = bid * 256 + tid;
        int wo = idx % 112, t1 = idx / 112;
        int ho = t1 % 112, n = t1 / 112;
        uint32_t xm = 0, vm = 0;
        #pragma unroll
        for (int ci = 0; ci < 3; ci++)
            #pragma unroll
            for (int kh = 0; kh < 3; kh++) {
                int hi = 2*ho + kh - 1;
                if ((unsigned)hi >= 224u) continue;
                #pragma unroll
                for (int kw = 0; kw < 3; kw++) {
                    int wi = 2*wo + kw - 1;
                    if ((unsigned)wi >= 224u) continue;
                    int t = ci*9 + kh*3 + kw;
                    vm |= (1u << t);
                    if (x[((n*3 + ci)*224 + hi)*224 + wi] >= 0.f) xm |= (1u << t);
                }
            }
        __syncthreads();
        double a2 = a2s;
        int V = __popc(vm);
        uint64_t bits = 0;
        for (int co = 0; co < 64; co++) {
            int m = __popc((~(xm ^ wm[co])) & vm);
            double h = a2 * (double)(2*m - V) + db1[co];
            if (h >= 0.0) bits |= (1ull << co);
        }
        p1[idx] = bits;
    } else {
        int rel = bid - 1568;                 // 0..159
        if (rel < 96) {                        // alpha partials (R6-identical)
            __shared__ double sd[256];
            int t = rel >> 5, c = rel & 31;
            const float* w; int n;
            if (t == 0)      { w = w2; n = 128*64*9; }
            else if (t == 1) { w = w3; n = 256*128*9; }
            else             { w = wf; n = 1000*256; }
            int per = (n + 31) / 32;
            int lo = c * per, hi = min(n, lo + per);
            double s0 = 0.0, s1 = 0.0, s2 = 0.0, s3 = 0.0;
            int i = lo + tid;
            for (; i + 768 < hi; i += 1024) {
                s0 += fabs((double)w[i]);
                s1 += fabs((double)w[i + 256]);
                s2 += fabs((double)w[i + 512]);
                s3 += fabs((double)w[i + 768]);
            }
            for (; i < hi; i += 256) s0 += fabs((double)w[i]);
            sd[tid] = (s0 + s1) + (s2 + s3);
            __syncthreads();
            for (int off = 128; off > 0; off >>= 1) {
                if (tid < off) sd[tid] += sd[tid + off];
                __syncthreads();
            }
            if (tid == 0) part[(t + 1)*32 + c] = sd[0];
        }
        int gw = rel * 4 + wid;               // ballot packing over 640 waves
        const int nw = 640;
        for (int w = gw; w < 1152; w += nw) {
            int co = w / 9, tap = w % 9, kh = tap / 3, kw = tap % 3;
            uint64_t b = __ballot(w2[((co*64 + lane)*3 + kh)*3 + kw] >= 0.f);
            if (lane == 0) wp2[w] = b;
        }
        for (int w = gw; w < 4608; w += nw) {
            int co = w / 18, r = w % 18, tap = r / 2, half = r & 1;
            int kh = tap / 3, kw = tap % 3;
            uint64_t b = __ballot(w3[((co*128 + half*64 + lane)*3 + kh)*3 + kw] >= 0.f);
            if (lane == 0) wp3t[(tap*2 + half)*256 + co] = b;
        }
        for (int w = gw; w < 4000; w += nw) {
            int o = w >> 2, j = w & 3;
            uint64_t b = __ballot(wf[o*256 + j*64 + lane] >= 0.f);
            if (lane == 0) wfp[w] = b;
        }
    }
}

// ---- K2: conv2, maskless inner loop + border-correction table. ----
// dot = dtab[co][cfg] - 2*mm_full where mm_full = sum_t popc(xs ^ w),
// xs zero-padded; dtab = 64V + 2*sum_{invalid t} popc(w_t). Integer-identical
// to the masked form (only ho==0 / wo==0 are borders for even input 112).
__global__ __launch_bounds__(256) void k2_conv2(
    const uint64_t* __restrict__ p1, const float* __restrict__ b2,
    const double* __restrict__ part, const uint64_t* __restrict__ wp2g,
    uint32_t* __restrict__ p2)
{
    __shared__ uint64_t wp[1152];      // [co][tap]
    __shared__ uint64_t xs[9*64];      // [tap][posLocal], zero-padded
    __shared__ int      dtab[128*4];   // [co][cfg]
    __shared__ double   db2[128];
    const int tid = threadIdx.x, lane = tid & 63;

    for (int i = tid; i < 1152; i += 256) wp[i] = wp2g[i];
    if (tid < 128) db2[tid] = (double)b2[tid];
    // zero-padded activation staging, layout [tap][pos] (conflict-free reads)
    for (int i = tid; i < 576; i += 256) {
        int t = i / 64, pl = i % 64;
        int pos = blockIdx.x * 64 + pl;
        int wo = pos % 56, t1 = pos / 56;
        int ho = t1 % 56, n = t1 / 56;
        int kh = t / 3, kw = t % 3;
        int hi = 2*ho + kh - 1, wi = 2*wo + kw - 1;
        bool ok = ((unsigned)hi < 112u) && ((unsigned)wi < 112u);
        xs[t*64 + pl] = ok ? p1[(n*112 + hi)*112 + wi] : 0ull;
    }
    // alpha2: serial 32-term sum (bitwise = R4's alpha_fin)
    double s = 0.0;
    for (int j = 0; j < 32; j++) s += part[32 + j];
    double a = s / (double)(128*64*9);
    double a2 = a * a;
    __syncthreads();
    // border-correction table (reads wp from LDS)
    if (tid < 128) {
        int co = tid;
        uint32_t P[9];
        #pragma unroll
        for (int t = 0; t < 9; t++) P[t] = __popcll(wp[co*9 + t]);
        int cT = P[0] + P[1] + P[2];      // taps lost when ho==0 (kh=0)
        int cL = P[0] + P[3] + P[6];      // taps lost when wo==0 (kw=0)
        int cC = P[0];
        #pragma unroll
        for (int cfg = 0; cfg < 4; cfg++) {
            int isT = cfg & 1, isL = (cfg >> 1) & 1;
            int V = 9 - 3*isT - 3*isL + (isT & isL);
            int corr = isT*cT + isL*cL - (isT & isL)*cC;
            dtab[co*4 + cfg] = 64*V + 2*corr;
        }
    }
    __syncthreads();

    int q = tid >> 6;
    int co0 = q * 32;
    int pos = blockIdx.x * 64 + lane;
    int wo = pos % 56, t1 = pos / 56;
    int ho = t1 % 56;
    int cfg = (ho == 0 ? 1 : 0) | (wo == 0 ? 2 : 0);
    uint64_t xv[9];
    #pragma unroll
    for (int t = 0; t < 9; t++) xv[t] = xs[t*64 + lane];
    uint32_t bits = 0;
    for (int c = 0; c < 32; c++) {
        int co = co0 + c;
        int mm = 0;
        #pragma unroll
        for (int t = 0; t < 9; t++)
            mm += __popcll(xv[t] ^ wp[co*9 + t]);
        int dot = dtab[co*4 + cfg] - 2*mm;
        double h = a2 * (double)dot + db2[co];
        if (h >= 0.0) bits |= (1u << c);
    }
    p2[pos*4 + q] = bits;
}

// ---- K3: conv3 + pool row partials. block=(n,ho), thread=co. ----
__global__ __launch_bounds__(256) void k3_conv3pool(
    const uint64_t* __restrict__ p2, const float* __restrict__ b3,
    const double* __restrict__ part, const uint64_t* __restrict__ wp3t,
    double* __restrict__ partial)
{
    __shared__ uint64_t xs[28*18];
    const int tid = threadIdx.x;
    int n = blockIdx.x / 28, ho = blockIdx.x % 28;

    double s = 0.0;
    for (int j = 0; j < 32; j++) s += part[64 + j];
    double a = s / (double)(256*128*9);
    double a2 = a * a;

    uint64_t w[18];
    #pragma unroll
    for (int i = 0; i < 18; i++) w[i] = wp3t[i*256 + tid];
    uint32_t P[9];
    #pragma unroll
    for (int t = 0; t < 9; t++) P[t] = __popcll(w[2*t]) + __popcll(w[2*t+1]);

    for (int i = tid; i < 504; i += 256) {
        int wo = i / 18, r = i % 18;
        int tap = r / 2, half = r % 2;
        int kh = tap / 3, kw = tap % 3;
        int hi = 2*ho + kh - 1, wi = 2*wo + kw - 1;
        bool ok = ((unsigned)hi < 56u) && ((unsigned)wi < 56u);
        xs[i] = ok ? p2[(size_t)((n*56 + hi)*56 + wi)*2 + half] : 0ull;
    }
    __syncthreads();

    bool htop = (ho == 0);
    int rv = htop ? 2 : 3;
    double bc = (double)b3[tid];
    double sum = 0.0;
    for (int wo = 0; wo < 28; wo++) {
        int mm = 0;
        #pragma unroll
        for (int t = 0; t < 18; t++)
            mm += __popcll(xs[wo*18 + t] ^ w[t]);
        bool wl = (wo == 0);
        int cv = wl ? 2 : 3;
        int corr = 0;
        if (htop) corr += P[0] + P[1] + P[2];
        if (wl)   corr += P[0] + P[3] + P[6];
        if (htop && wl) corr -= P[0];
        int dot = 128*(rv*cv) - 2*mm + 2*corr;
        double h = a2 * (double)dot + bc;
        h = fmin(fmax(h, -1.0), 1.0);
        sum += h;
    }
    partial[(size_t)(n*28 + ho)*256 + tid] = sum;
}

// ---- K4: pool finalize (ho-order sum) + FC, block = image n ----
__global__ __launch_bounds__(256) void k4_poolfc(
    const double* __restrict__ partial, const uint64_t* __restrict__ wfp,
    const float* __restrict__ bf, const double* __restrict__ part,
    float* __restrict__ out)
{
    __shared__ uint64_t spl[4];
    const int tid = threadIdx.x, lane = tid & 63;
    int n = blockIdx.x;
    double s = 0.0;
    for (int c = 0; c < 28; c++) s += partial[(size_t)(n*28 + c)*256 + tid];
    uint64_t bal = __ballot((s / 784.0) >= 0.0);
    if (lane == 0) spl[tid >> 6] = bal;

    double sa = 0.0;
    for (int j = 0; j < 32; j++) sa += part[96 + j];
    double a = sa / (double)(1000*256);
    double aa = a * a;
    __syncthreads();
    uint64_t s0 = spl[0], s1 = spl[1], s2 = spl[2], s3 = spl[3];
    for (int o = tid; o < 1000; o += 256) {
        int m = __popcll(s0 ^ wfp[o*4]) + __popcll(s1 ^ wfp[o*4+1])
              + __popcll(s2 ^ wfp[o*4+2]) + __popcll(s3 ^ wfp[o*4+3]);
        out[n*1000 + o] = (float)(aa * (double)(256 - 2*m) + (double)bf[o]);
    }
}

extern "C" void kernel_launch(void* const* d_in, const int* in_sizes, int n_in,
                              void* d_out, int out_size, void* d_ws, size_t ws_size,
                              hipStream_t stream) {
    const float* x  = (const float*)d_in[0];
    const float* w1 = (const float*)d_in[1];
    const float* b1 = (const float*)d_in[2];
    const float* w2 = (const float*)d_in[3];
    const float* b2 = (const float*)d_in[4];
    const float* w3 = (const float*)d_in[5];
    const float* b3 = (const float*)d_in[6];
    const float* wf = (const float*)d_in[7];
    const float* bf = (const float*)d_in[8];

    char* ws = (char*)d_ws;
    uint64_t* wp2    = (uint64_t*)(ws + WP2_OFF);
    uint64_t* wp3t   = (uint64_t*)(ws + WP3T_OFF);
    uint64_t* wfp    = (uint64_t*)(ws + WFP_OFF);
    double*   part   = (double*)  (ws + PART_OFF);
    uint64_t* p1     = (uint64_t*)(ws + P1_OFF);
    uint32_t* p2     = (uint32_t*)(ws + P2_OFF);
    double*   poolp  = (double*)  (ws + POOLP_OFF);
    float*    out    = (float*)   d_out;

    hipLaunchKernelGGL(k1_conv1_pack, dim3(1728), dim3(256), 0, stream,
                       x, w1, b1, w2, w3, wf, wp2, wp3t, wfp, part, p1);
    hipLaunchKernelGGL(k2_conv2,      dim3(1568), dim3(256), 0, stream,
                       p1, b2, part, wp2, p2);
    hipLaunchKernelGGL(k3_conv3pool,  dim3(896),  dim3(256), 0, stream,
                       (const uint64_t*)p2, b3, part, wp3t, poolp);
    hipLaunchKernelGGL(k4_poolfc,     dim3(32),   dim3(256), 0, stream,
                       poolp, wfp, bf, part, out);
}

// Round 8
// 145.955 us; speedup vs baseline: 4.6475x; 1.0008x over previous
//
#include <hip/hip_runtime.h>
#include <stdint.h>
#include <math.h>

// ---------------------------------------------------------------------------
// XNOR-Net forward: 3 binarized stride-2 convs + global avg pool + binary FC.
// Exact integer popcount dots; sign decisions via exact integer thresholds
// (monotone predicate, fixup against the identical f64 expression).
// Budget (R5-R7 evidence): ~88us fixed harness work (268MB ws poison fill at
// ~43us + restores + replay overhead); launch gap ~1.5us.
// R8: (a) K1/K2 epilogues integer-threshold only (f64 removed from hot loop);
// (b) K2 handles 2 positions/lane (784 blocks) halving weight-LDS traffic
// and per-block staging. K3 keeps f64 (clip values needed for pooling).
// ---------------------------------------------------------------------------

// ws layout (bytes)
#define WP2_OFF    2048ull     // u64[128*9]       layer2 packed weights [co][tap]
#define WP3T_OFF   16384ull    // u64[18*256]      layer3 packed weights [tap*2+half][co]
#define WFP_OFF    65536ull    // u64[1000*4]      fc packed weights
#define PART_OFF   100352ull   // double[128]      alpha partials (t=1:w2,2:w3,3:wf)
#define P1_OFF     102400ull   // u64[32*112*112]  layer1 out signs (bit=co)
#define P2_OFF     3313664ull  // u32[32*56*56*4]  layer2 out signs (quarters)
#define POOLP_OFF  4919296ull  // double[32*28*256] conv3 row-partial pool sums

// ---- K1: conv1 (blocks 0..1567) + weight pack / alpha partials (1568..1727)
__global__ __launch_bounds__(256) void k1_conv1_pack(
    const float* __restrict__ x,  const float* __restrict__ w1, const float* __restrict__ b1,
    const float* __restrict__ w2, const float* __restrict__ w3, const float* __restrict__ wf,
    uint64_t* __restrict__ wp2, uint64_t* __restrict__ wp3t, uint64_t* __restrict__ wfp,
    double* __restrict__ part, uint64_t* __restrict__ p1)
{
    const int tid = threadIdx.x, lane = tid & 63, wid = tid >> 6, bid = blockIdx.x;
    if (bid < 1568) {
        __shared__ double a2s;
        __shared__ uint32_t wm[64];
        __shared__ int Ts[64];
        // wave 0: alpha1 (27 coalesced loads/lane + butterfly; deterministic)
        if (wid == 0) {
            double s = 0.0;
            #pragma unroll
            for (int i = 0; i < 27; i++) s += fabs((double)w1[lane + i*64]);
            #pragma unroll
            for (int off = 1; off < 64; off <<= 1) s += __shfl_xor(s, off, 64);
            if (lane == 0) { double a = s / 1728.0; a2s = a * a; }
        } else if (wid == 1) {          // wave 1: wm1 pack
            uint32_t m = 0;
            for (int t = 0; t < 27; t++) {
                int ci = t / 9, r = t % 9, kh = r / 3, kw = r % 3;
                if (w1[((lane*3 + ci)*3 + kh)*3 + kw] >= 0.f) m |= (1u << t);
            }
            wm[lane] = m;
        }
        // all threads: gather 27 sign taps (long-latency loads overlap setup)
        int idx = bid * 256 + tid;
        int wo = idx % 112, t1 = idx / 112;
        int ho = t1 % 112, n = t1 / 112;
        uint32_t xm = 0, vm = 0;
        #pragma unroll
        for (int ci = 0; ci < 3; ci++)
            #pragma unroll
            for (int kh = 0; kh < 3; kh++) {
                int hi = 2*ho + kh - 1;
                if ((unsigned)hi >= 224u) continue;
                #pragma unroll
                for (int kw = 0; kw < 3; kw++) {
                    int wi = 2*wo + kw - 1;
                    if ((unsigned)wi >= 224u) continue;
                    int t = ci*9 + kh*3 + kw;
                    vm |= (1u << t);
                    if (x[((n*3 + ci)*224 + hi)*224 + wi] >= 0.f) xm |= (1u << t);
                }
            }
        __syncthreads();
        // tid<64: exact integer threshold: smallest k in [-27,28] with
        // a2*k + b1 >= 0 (same expression as the f64 epilogue; monotone in k)
        if (tid < 64) {
            double a2 = a2s, b = (double)b1[tid];
            int k = (int)ceil(-b / a2);
            k = max(-27, min(28, k));
            while (k > -27 && (a2 * (double)(k - 1) + b >= 0.0)) k--;
            while (k <= 27 && !(a2 * (double)k + b >= 0.0)) k++;
            Ts[tid] = k;
        }
        __syncthreads();
        int V = __popc(vm);
        uint64_t bits = 0;
        for (int co = 0; co < 64; co++) {
            int m = __popc((~(xm ^ wm[co])) & vm);
            if (2*m - V >= Ts[co]) bits |= (1ull << co);
        }
        p1[idx] = bits;
    } else {
        int rel = bid - 1568;                 // 0..159
        if (rel < 96) {                        // alpha partials (R6-identical)
            __shared__ double sd[256];
            int t = rel >> 5, c = rel & 31;
            const float* w; int n;
            if (t == 0)      { w = w2; n = 128*64*9; }
            else if (t == 1) { w = w3; n = 256*128*9; }
            else             { w = wf; n = 1000*256; }
            int per = (n + 31) / 32;
            int lo = c * per, hi = min(n, lo + per);
            double s0 = 0.0, s1 = 0.0, s2 = 0.0, s3 = 0.0;
            int i = lo + tid;
            for (; i + 768 < hi; i += 1024) {
                s0 += fabs((double)w[i]);
                s1 += fabs((double)w[i + 256]);
                s2 += fabs((double)w[i + 512]);
                s3 += fabs((double)w[i + 768]);
            }
            for (; i < hi; i += 256) s0 += fabs((double)w[i]);
            sd[tid] = (s0 + s1) + (s2 + s3);
            __syncthreads();
            for (int off = 128; off > 0; off >>= 1) {
                if (tid < off) sd[tid] += sd[tid + off];
                __syncthreads();
            }
            if (tid == 0) part[(t + 1)*32 + c] = sd[0];
        }
        int gw = rel * 4 + wid;               // ballot packing over 640 waves
        const int nw = 640;
        for (int w = gw; w < 1152; w += nw) {
            int co = w / 9, tap = w % 9, kh = tap / 3, kw = tap % 3;
            uint64_t b = __ballot(w2[((co*64 + lane)*3 + kh)*3 + kw] >= 0.f);
            if (lane == 0) wp2[w] = b;
        }
        for (int w = gw; w < 4608; w += nw) {
            int co = w / 18, r = w % 18, tap = r / 2, half = r & 1;
            int kh = tap / 3, kw = tap % 3;
            uint64_t b = __ballot(w3[((co*128 + half*64 + lane)*3 + kh)*3 + kw] >= 0.f);
            if (lane == 0) wp3t[(tap*2 + half)*256 + co] = b;
        }
        for (int w = gw; w < 4000; w += nw) {
            int o = w >> 2, j = w & 3;
            uint64_t b = __ballot(wf[o*256 + j*64 + lane] >= 0.f);
            if (lane == 0) wfp[w] = b;
        }
    }
}

// ---- K2: conv2, 2 positions/lane, integer-threshold epilogue. ----
// cond: h>=0 <=> dot >= T[co] <=> mm <= M[co][cfg] = (dtab-T)>>1 where
// dtab = 64V + 2*sum_{invalid taps} popc(w), mm = popcount over zero-padded.
__global__ __launch_bounds__(256) void k2_conv2(
    const uint64_t* __restrict__ p1, const float* __restrict__ b2,
    const double* __restrict__ part, const uint64_t* __restrict__ wp2g,
    uint32_t* __restrict__ p2)
{
    __shared__ uint64_t wp[1152];      // [co][tap]
    __shared__ uint64_t xs[1152];      // [tap][128 positions], zero-padded
    __shared__ int      M[128*4];      // [co][cfg] popcount bound
    const int tid = threadIdx.x, lane = tid & 63;

    for (int i = tid; i < 1152; i += 256) wp[i] = wp2g[i];
    for (int i = tid; i < 1152; i += 256) {
        int t = i >> 7, pl = i & 127;
        int pos = blockIdx.x * 128 + pl;
        int wo = pos % 56, t1 = pos / 56;
        int ho = t1 % 56, n = t1 / 56;
        int kh = t / 3, kw = t % 3;
        int hi = 2*ho + kh - 1, wi = 2*wo + kw - 1;
        bool ok = ((unsigned)hi < 112u) && ((unsigned)wi < 112u);
        xs[i] = ok ? p1[(n*112 + hi)*112 + wi] : 0ull;
    }
    __syncthreads();
    if (tid < 128) {
        int co = tid;
        // alpha2: serial 32-term sum (bitwise = R4's alpha_fin)
        double s = 0.0;
        for (int j = 0; j < 32; j++) s += part[32 + j];
        double a = s / (double)(128*64*9);
        double a2 = a * a, b = (double)b2[co];
        // exact threshold on dot in [-576,576]
        int k = (int)ceil(-b / a2);
        k = max(-577, min(578, k));
        while (k > -577 && (a2 * (double)(k - 1) + b >= 0.0)) k--;
        while (k <= 577 && !(a2 * (double)k + b >= 0.0)) k++;
        uint32_t P[9];
        #pragma unroll
        for (int t = 0; t < 9; t++) P[t] = __popcll(wp[co*9 + t]);
        int cT = P[0] + P[1] + P[2];
        int cL = P[0] + P[3] + P[6];
        int cC = P[0];
        #pragma unroll
        for (int cfg = 0; cfg < 4; cfg++) {
            int isT = cfg & 1, isL = (cfg >> 1) & 1;
            int V = 9 - 3*isT - 3*isL + (isT & isL);
            int corr = isT*cT + isL*cL - (isT & isL)*cC;
            int dtab = 64*V + 2*corr;
            M[co*4 + cfg] = (dtab - k) >> 1;   // floor division (arith shift)
        }
    }
    __syncthreads();

    int q = tid >> 6;
    int co0 = q * 32;
    int pos0 = blockIdx.x * 128 + lane;
    int pos1 = pos0 + 64;
    int wo0 = pos0 % 56, ho0 = (pos0 / 56) % 56;
    int wo1 = pos1 % 56, ho1 = (pos1 / 56) % 56;
    int cfg0 = (ho0 == 0 ? 1 : 0) | (wo0 == 0 ? 2 : 0);
    int cfg1 = (ho1 == 0 ? 1 : 0) | (wo1 == 0 ? 2 : 0);
    uint64_t xv0[9], xv1[9];
    #pragma unroll
    for (int t = 0; t < 9; t++) { xv0[t] = xs[t*128 + lane]; xv1[t] = xs[t*128 + 64 + lane]; }
    uint32_t bits0 = 0, bits1 = 0;
    for (int c = 0; c < 32; c++) {
        int co = co0 + c;
        int mm0 = 0, mm1 = 0;
        #pragma unroll
        for (int t = 0; t < 9; t++) {
            uint64_t w = wp[co*9 + t];
            mm0 += __popcll(xv0[t] ^ w);
            mm1 += __popcll(xv1[t] ^ w);
        }
        if (mm0 <= M[co*4 + cfg0]) bits0 |= (1u << c);
        if (mm1 <= M[co*4 + cfg1]) bits1 |= (1u << c);
    }
    p2[pos0*4 + q] = bits0;
    p2[pos1*4 + q] = bits1;
}

// ---- K3: conv3 + pool row partials. block=(n,ho), thread=co. ----
__global__ __launch_bounds__(256) void k3_conv3pool(
    const uint64_t* __restrict__ p2, const float* __restrict__ b3,
    const double* __restrict__ part, const uint64_t* __restrict__ wp3t,
    double* __restrict__ partial)
{
    __shared__ uint64_t xs[28*18];
    const int tid = threadIdx.x;
    int n = blockIdx.x / 28, ho = blockIdx.x % 28;

    double s = 0.0;
    for (int j = 0; j < 32; j++) s += part[64 + j];
    double a = s / (double)(256*128*9);
    double a2 = a * a;

    uint64_t w[18];
    #pragma unroll
    for (int i = 0; i < 18; i++) w[i] = wp3t[i*256 + tid];
    uint32_t P[9];
    #pragma unroll
    for (int t = 0; t < 9; t++) P[t] = __popcll(w[2*t]) + __popcll(w[2*t+1]);

    for (int i = tid; i < 504; i += 256) {
        int wo = i / 18, r = i % 18;
        int tap = r / 2, half = r % 2;
        int kh = tap / 3, kw = tap % 3;
        int hi = 2*ho + kh - 1, wi = 2*wo + kw - 1;
        bool ok = ((unsigned)hi < 56u) && ((unsigned)wi < 56u);
        xs[i] = ok ? p2[(size_t)((n*56 + hi)*56 + wi)*2 + half] : 0ull;
    }
    __syncthreads();

    bool htop = (ho == 0);
    int rv = htop ? 2 : 3;
    double bc = (double)b3[tid];
    double sum = 0.0;
    for (int wo = 0; wo < 28; wo++) {
        int mm = 0;
        #pragma unroll
        for (int t = 0; t < 18; t++)
            mm += __popcll(xs[wo*18 + t] ^ w[t]);
        bool wl = (wo == 0);
        int cv = wl ? 2 : 3;
        int corr = 0;
        if (htop) corr += P[0] + P[1] + P[2];
        if (wl)   corr += P[0] + P[3] + P[6];
        if (htop && wl) corr -= P[0];
        int dot = 128*(rv*cv) - 2*mm + 2*corr;
        double h = a2 * (double)dot + bc;
        h = fmin(fmax(h, -1.0), 1.0);
        sum += h;
    }
    partial[(size_t)(n*28 + ho)*256 + tid] = sum;
}

// ---- K4: pool finalize (ho-order sum) + FC, block = image n ----
__global__ __launch_bounds__(256) void k4_poolfc(
    const double* __restrict__ partial, const uint64_t* __restrict__ wfp,
    const float* __restrict__ bf, const double* __restrict__ part,
    float* __restrict__ out)
{
    __shared__ uint64_t spl[4];
    const int tid = threadIdx.x, lane = tid & 63;
    int n = blockIdx.x;
    double s = 0.0;
    for (int c = 0; c < 28; c++) s += partial[(size_t)(n*28 + c)*256 + tid];
    uint64_t bal = __ballot((s / 784.0) >= 0.0);
    if (lane == 0) spl[tid >> 6] = bal;

    double sa = 0.0;
    for (int j = 0; j < 32; j++) sa += part[96 + j];
    double a = sa / (double)(1000*256);
    double aa = a * a;
    __syncthreads();
    uint64_t s0 = spl[0], s1 = spl[1], s2 = spl[2], s3 = spl[3];
    for (int o = tid; o < 1000; o += 256) {
        int m = __popcll(s0 ^ wfp[o*4]) + __popcll(s1 ^ wfp[o*4+1])
              + __popcll(s2 ^ wfp[o*4+2]) + __popcll(s3 ^ wfp[o*4+3]);
        out[n*1000 + o] = (float)(aa * (double)(256 - 2*m) + (double)bf[o]);
    }
}

extern "C" void kernel_launch(void* const* d_in, const int* in_sizes, int n_in,
                              void* d_out, int out_size, void* d_ws, size_t ws_size,
                              hipStream_t stream) {
    const float* x  = (const float*)d_in[0];
    const float* w1 = (const float*)d_in[1];
    const float* b1 = (const float*)d_in[2];
    const float* w2 = (const float*)d_in[3];
    const float* b2 = (const float*)d_in[4];
    const float* w3 = (const float*)d_in[5];
    const float* b3 = (const float*)d_in[6];
    const float* wf = (const float*)d_in[7];
    const float* bf = (const float*)d_in[8];

    char* ws = (char*)d_ws;
    uint64_t* wp2    = (uint64_t*)(ws + WP2_OFF);
    uint64_t* wp3t   = (uint64_t*)(ws + WP3T_OFF);
    uint64_t* wfp    = (uint64_t*)(ws + WFP_OFF);
    double*   part   = (double*)  (ws + PART_OFF);
    uint64_t* p1     = (uint64_t*)(ws + P1_OFF);
    uint32_t* p2     = (uint32_t*)(ws + P2_OFF);
    double*   poolp  = (double*)  (ws + POOLP_OFF);
    float*    out    = (float*)   d_out;

    hipLaunchKernelGGL(k1_conv1_pack, dim3(1728), dim3(256), 0, stream,
                       x, w1, b1, w2, w3, wf, wp2, wp3t, wfp, part, p1);
    hipLaunchKernelGGL(k2_conv2,      dim3(784),  dim3(256), 0, stream,
                       p1, b2, part, wp2, p2);
    hipLaunchKernelGGL(k3_conv3pool,  dim3(896),  dim3(256), 0, stream,
                       (const uint64_t*)p2, b3, part, wp3t, poolp);
    hipLaunchKernelGGL(k4_poolfc,     dim3(32),   dim3(256), 0, stream,
                       poolp, wfp, bf, part, out);
}

// Round 9
// 142.836 us; speedup vs baseline: 4.7489x; 1.0218x over previous
//
#include <hip/hip_runtime.h>
#include <stdint.h>
#include <math.h>

// ---------------------------------------------------------------------------
// XNOR-Net forward: 3 binarized stride-2 convs + global avg pool + binary FC.
// Exact integer popcount dots; sign decisions via exact integer thresholds.
// Ledger (R4-R8): ~85us fixed harness work; per-launch gap ~1.5us; K2~4,
// K3~7, K4~3 -> K1 ~35us, memory-front-end bound (27 scattered stride-2
// global loads/thread, untouched since R1; its ALU-side changes were neutral).
// R9: K1 conv restructured: block=(n, 4 out rows); stage 27 input row-segs
// to LDS with coalesced float4 loads; pack sign bits to u32 words (bank-
// swizzled); extract 27-bit masks via 64-bit funnel windows. Bit-identical
// p1 (same sign compares, same vm/m/Ts integers). K2/K3/K4 unchanged.
// ---------------------------------------------------------------------------

// ws layout (bytes)
#define WP2_OFF    2048ull     // u64[128*9]       layer2 packed weights [co][tap]
#define WP3T_OFF   16384ull    // u64[18*256]      layer3 packed weights [tap*2+half][co]
#define WFP_OFF    65536ull    // u64[1000*4]      fc packed weights
#define PART_OFF   100352ull   // double[128]      alpha partials (t=1:w2,2:w3,3:wf)
#define P1_OFF     102400ull   // u64[32*112*112]  layer1 out signs (bit=co)
#define P2_OFF     3313664ull  // u32[32*56*56*4]  layer2 out signs (quarters)
#define POOLP_OFF  4919296ull  // double[32*28*256] conv3 row-partial pool sums

// ---- K1: conv1 (blocks 0..895: n=bid/28, 4 output rows each) +
//          weight pack / alpha partials (blocks 896..1055)
__global__ __launch_bounds__(256) void k1_conv1_pack(
    const float* __restrict__ x,  const float* __restrict__ w1, const float* __restrict__ b1,
    const float* __restrict__ w2, const float* __restrict__ w3, const float* __restrict__ wf,
    uint64_t* __restrict__ wp2, uint64_t* __restrict__ wp3t, uint64_t* __restrict__ wfp,
    double* __restrict__ part, uint64_t* __restrict__ p1)
{
    const int tid = threadIdx.x, lane = tid & 63, wid = tid >> 6, bid = blockIdx.x;
    if (bid < 896) {
        __shared__ float4   xf4[1512];        // 27 segs x 56 float4 (24.2 KB)
        __shared__ uint32_t xb[216];          // 27 segs x 8 u32 sign-bit words
        __shared__ uint32_t wm[64];
        __shared__ int      Ts[64];
        __shared__ double   a2s;
        const float* xf = (const float*)xf4;

        int n = bid / 28, hb = bid % 28;
        int ho0 = hb * 4;
        int hi0 = 2 * ho0 - 1;                // first staged input row (may be -1)

        // prelude (waves 0/1) overlapped with float4 staging below
        if (wid == 0) {                       // alpha1: coalesced + butterfly
            double s = 0.0;
            #pragma unroll
            for (int i = 0; i < 27; i++) s += fabs((double)w1[lane + i*64]);
            #pragma unroll
            for (int off = 1; off < 64; off <<= 1) s += __shfl_xor(s, off, 64);
            if (lane == 0) { double a = s / 1728.0; a2s = a * a; }
        } else if (wid == 1) {                // wm1 pack (27-bit masks)
            uint32_t m = 0;
            for (int t = 0; t < 27; t++) {
                int ci = t / 9, r = t % 9, kh = r / 3, kw = r % 3;
                if (w1[((lane*3 + ci)*3 + kh)*3 + kw] >= 0.f) m |= (1u << t);
            }
            wm[lane] = m;
        }
        // stage 27 row segments (seg = ci*9 + r, hi = hi0 + r), float4 coalesced
        const float4* xg = (const float4*)x;
        for (int i = tid; i < 1512; i += 256) {
            int seg = i / 56, f4 = i % 56;
            int ci = seg / 9, r = seg % 9;
            int hi = hi0 + r;
            float4 v = make_float4(0.f, 0.f, 0.f, 0.f);
            if ((unsigned)hi < 224u) v = xg[((n*3 + ci)*224 + hi)*56 + f4];
            xf4[i] = v;
        }
        __syncthreads();
        // integer threshold: smallest k with a2*k + b1 >= 0 (same f64 expr)
        if (tid < 64) {
            double a2 = a2s, b = (double)b1[tid];
            int k = (int)ceil(-b / a2);
            k = max(-27, min(28, k));
            while (k > -27 && (a2 * (double)(k - 1) + b >= 0.0)) k--;
            while (k <= 27 && !(a2 * (double)k + b >= 0.0)) k++;
            Ts[tid] = k;
        }
        // pack sign bits: thread t<189 owns u32 word j of seg (7 words = 224 cols);
        // bank-swizzled LDS reads (bit (k+t)&31 of the 32-col window)
        if (tid < 189) {
            int seg = tid / 7, j = tid % 7;
            uint32_t u = 0;
            #pragma unroll
            for (int k = 0; k < 32; k++) {
                int o = (k + tid) & 31;
                if (xf[seg*224 + j*32 + o] >= 0.f) u |= (1u << o);
            }
            xb[seg*8 + j] = u;
        } else if (tid < 216) {
            xb[(tid - 189)*8 + 7] = 0u;       // pad word (cols 224..255)
        }
        __syncthreads();

        // compute 448 outputs (2 per thread)
        for (int pass = 0; pass < 2; pass++) {
            int s = tid + pass*256;
            if (s >= 448) break;
            int dho = s / 112, wo = s % 112;
            int hop = ho0 + dho;
            uint32_t vm = 0x7FFFFFFu;
            if (hop == 0) vm &= ~0x1C0E07u;   // kh=0 taps
            if (wo == 0)  vm &= ~0x1249249u;  // kw=0 taps
            int c0 = 2*wo - 1;
            uint32_t xm = 0;
            if (wo > 0) {
                int w0 = c0 >> 5, sh = c0 & 31;
                #pragma unroll
                for (int ci = 0; ci < 3; ci++)
                    #pragma unroll
                    for (int kh = 0; kh < 3; kh++) {
                        int seg = ci*9 + 2*dho + kh;
                        uint64_t dw = (uint64_t)xb[seg*8 + w0]
                                    | ((uint64_t)xb[seg*8 + w0 + 1] << 32);
                        xm |= (uint32_t)((dw >> sh) & 7u) << (ci*9 + kh*3);
                    }
            } else {
                #pragma unroll
                for (int ci = 0; ci < 3; ci++)
                    #pragma unroll
                    for (int kh = 0; kh < 3; kh++) {
                        int seg = ci*9 + 2*dho + kh;
                        xm |= ((xb[seg*8] << 1) & 6u) << (ci*9 + kh*3);
                    }
            }
            int V = __popc(vm);
            uint64_t bits = 0;
            for (int co = 0; co < 64; co++) {
                int m = __popc((~(xm ^ wm[co])) & vm);
                if (2*m - V >= Ts[co]) bits |= (1ull << co);
            }
            p1[(n*112 + hop)*112 + wo] = bits;
        }
    } else {
        int rel = bid - 896;                  // 0..159
        if (rel < 96) {                        // alpha partials (R6-identical)
            __shared__ double sd[256];
            int t = rel >> 5, c = rel & 31;
            const float* w; int n;
            if (t == 0)      { w = w2; n = 128*64*9; }
            else if (t == 1) { w = w3; n = 256*128*9; }
            else             { w = wf; n = 1000*256; }
            int per = (n + 31) / 32;
            int lo = c * per, hi = min(n, lo + per);
            double s0 = 0.0, s1 = 0.0, s2 = 0.0, s3 = 0.0;
            int i = lo + tid;
            for (; i + 768 < hi; i += 1024) {
                s0 += fabs((double)w[i]);
                s1 += fabs((double)w[i + 256]);
                s2 += fabs((double)w[i + 512]);
                s3 += fabs((double)w[i + 768]);
            }
            for (; i < hi; i += 256) s0 += fabs((double)w[i]);
            sd[tid] = (s0 + s1) + (s2 + s3);
            __syncthreads();
            for (int off = 128; off > 0; off >>= 1) {
                if (tid < off) sd[tid] += sd[tid + off];
                __syncthreads();
            }
            if (tid == 0) part[(t + 1)*32 + c] = sd[0];
        }
        int gw = rel * 4 + wid;               // ballot packing over 640 waves
        const int nw = 640;
        for (int w = gw; w < 1152; w += nw) {
            int co = w / 9, tap = w % 9, kh = tap / 3, kw = tap % 3;
            uint64_t b = __ballot(w2[((co*64 + lane)*3 + kh)*3 + kw] >= 0.f);
            if (lane == 0) wp2[w] = b;
        }
        for (int w = gw; w < 4608; w += nw) {
            int co = w / 18, r = w % 18, tap = r / 2, half = r & 1;
            int kh = tap / 3, kw = tap % 3;
            uint64_t b = __ballot(w3[((co*128 + half*64 + lane)*3 + kh)*3 + kw] >= 0.f);
            if (lane == 0) wp3t[(tap*2 + half)*256 + co] = b;
        }
        for (int w = gw; w < 4000; w += nw) {
            int o = w >> 2, j = w & 3;
            uint64_t b = __ballot(wf[o*256 + j*64 + lane] >= 0.f);
            if (lane == 0) wfp[w] = b;
        }
    }
}

// ---- K2: conv2, 2 positions/lane, integer-threshold epilogue (R8). ----
__global__ __launch_bounds__(256) void k2_conv2(
    const uint64_t* __restrict__ p1, const float* __restrict__ b2,
    const double* __restrict__ part, const uint64_t* __restrict__ wp2g,
    uint32_t* __restrict__ p2)
{
    __shared__ uint64_t wp[1152];      // [co][tap]
    __shared__ uint64_t xs[1152];      // [tap][128 positions], zero-padded
    __shared__ int      M[128*4];      // [co][cfg] popcount bound
    const int tid = threadIdx.x, lane = tid & 63;

    for (int i = tid; i < 1152; i += 256) wp[i] = wp2g[i];
    for (int i = tid; i < 1152; i += 256) {
        int t = i >> 7, pl = i & 127;
        int pos = blockIdx.x * 128 + pl;
        int wo = pos % 56, t1 = pos / 56;
        int ho = t1 % 56, n = t1 / 56;
        int kh = t / 3, kw = t % 3;
        int hi = 2*ho + kh - 1, wi = 2*wo + kw - 1;
        bool ok = ((unsigned)hi < 112u) && ((unsigned)wi < 112u);
        xs[i] = ok ? p1[(n*112 + hi)*112 + wi] : 0ull;
    }
    __syncthreads();
    if (tid < 128) {
        int co = tid;
        double s = 0.0;
        for (int j = 0; j < 32; j++) s += part[32 + j];
        double a = s / (double)(128*64*9);
        double a2 = a * a, b = (double)b2[co];
        int k = (int)ceil(-b / a2);
        k = max(-577, min(578, k));
        while (k > -577 && (a2 * (double)(k - 1) + b >= 0.0)) k--;
        while (k <= 577 && !(a2 * (double)k + b >= 0.0)) k++;
        uint32_t P[9];
        #pragma unroll
        for (int t = 0; t < 9; t++) P[t] = __popcll(wp[co*9 + t]);
        int cT = P[0] + P[1] + P[2];
        int cL = P[0] + P[3] + P[6];
        int cC = P[0];
        #pragma unroll
        for (int cfg = 0; cfg < 4; cfg++) {
            int isT = cfg & 1, isL = (cfg >> 1) & 1;
            int V = 9 - 3*isT - 3*isL + (isT & isL);
            int corr = isT*cT + isL*cL - (isT & isL)*cC;
            int dtab = 64*V + 2*corr;
            M[co*4 + cfg] = (dtab - k) >> 1;
        }
    }
    __syncthreads();

    int q = tid >> 6;
    int co0 = q * 32;
    int pos0 = blockIdx.x * 128 + lane;
    int pos1 = pos0 + 64;
    int wo0 = pos0 % 56, ho0 = (pos0 / 56) % 56;
    int wo1 = pos1 % 56, ho1 = (pos1 / 56) % 56;
    int cfg0 = (ho0 == 0 ? 1 : 0) | (wo0 == 0 ? 2 : 0);
    int cfg1 = (ho1 == 0 ? 1 : 0) | (wo1 == 0 ? 2 : 0);
    uint64_t xv0[9], xv1[9];
    #pragma unroll
    for (int t = 0; t < 9; t++) { xv0[t] = xs[t*128 + lane]; xv1[t] = xs[t*128 + 64 + lane]; }
    uint32_t bits0 = 0, bits1 = 0;
    for (int c = 0; c < 32; c++) {
        int co = co0 + c;
        int mm0 = 0, mm1 = 0;
        #pragma unroll
        for (int t = 0; t < 9; t++) {
            uint64_t w = wp[co*9 + t];
            mm0 += __popcll(xv0[t] ^ w);
            mm1 += __popcll(xv1[t] ^ w);
        }
        if (mm0 <= M[co*4 + cfg0]) bits0 |= (1u << c);
        if (mm1 <= M[co*4 + cfg1]) bits1 |= (1u << c);
    }
    p2[pos0*4 + q] = bits0;
    p2[pos1*4 + q] = bits1;
}

// ---- K3: conv3 + pool row partials. block=(n,ho), thread=co. ----
__global__ __launch_bounds__(256) void k3_conv3pool(
    const uint64_t* __restrict__ p2, const float* __restrict__ b3,
    const double* __restrict__ part, const uint64_t* __restrict__ wp3t,
    double* __restrict__ partial)
{
    __shared__ uint64_t xs[28*18];
    const int tid = threadIdx.x;
    int n = blockIdx.x / 28, ho = blockIdx.x % 28;

    double s = 0.0;
    for (int j = 0; j < 32; j++) s += part[64 + j];
    double a = s / (double)(256*128*9);
    double a2 = a * a;

    uint64_t w[18];
    #pragma unroll
    for (int i = 0; i < 18; i++) w[i] = wp3t[i*256 + tid];
    uint32_t P[9];
    #pragma unroll
    for (int t = 0; t < 9; t++) P[t] = __popcll(w[2*t]) + __popcll(w[2*t+1]);

    for (int i = tid; i < 504; i += 256) {
        int wo = i / 18, r = i % 18;
        int tap = r / 2, half = r % 2;
        int kh = tap / 3, kw = tap % 3;
        int hi = 2*ho + kh - 1, wi = 2*wo + kw - 1;
        bool ok = ((unsigned)hi < 56u) && ((unsigned)wi < 56u);
        xs[i] = ok ? p2[(size_t)((n*56 + hi)*56 + wi)*2 + half] : 0ull;
    }
    __syncthreads();

    bool htop = (ho == 0);
    int rv = htop ? 2 : 3;
    double bc = (double)b3[tid];
    double sum = 0.0;
    for (int wo = 0; wo < 28; wo++) {
        int mm = 0;
        #pragma unroll
        for (int t = 0; t < 18; t++)
            mm += __popcll(xs[wo*18 + t] ^ w[t]);
        bool wl = (wo == 0);
        int cv = wl ? 2 : 3;
        int corr = 0;
        if (htop) corr += P[0] + P[1] + P[2];
        if (wl)   corr += P[0] + P[3] + P[6];
        if (htop && wl) corr -= P[0];
        int dot = 128*(rv*cv) - 2*mm + 2*corr;
        double h = a2 * (double)dot + bc;
        h = fmin(fmax(h, -1.0), 1.0);
        sum += h;
    }
    partial[(size_t)(n*28 + ho)*256 + tid] = sum;
}

// ---- K4: pool finalize (ho-order sum) + FC, block = image n ----
__global__ __launch_bounds__(256) void k4_poolfc(
    const double* __restrict__ partial, const uint64_t* __restrict__ wfp,
    const float* __restrict__ bf, const double* __restrict__ part,
    float* __restrict__ out)
{
    __shared__ uint64_t spl[4];
    const int tid = threadIdx.x, lane = tid & 63;
    int n = blockIdx.x;
    double s = 0.0;
    for (int c = 0; c < 28; c++) s += partial[(size_t)(n*28 + c)*256 + tid];
    uint64_t bal = __ballot((s / 784.0) >= 0.0);
    if (lane == 0) spl[tid >> 6] = bal;

    double sa = 0.0;
    for (int j = 0; j < 32; j++) sa += part[96 + j];
    double a = sa / (double)(1000*256);
    double aa = a * a;
    __syncthreads();
    uint64_t s0 = spl[0], s1 = spl[1], s2 = spl[2], s3 = spl[3];
    for (int o = tid; o < 1000; o += 256) {
        int m = __popcll(s0 ^ wfp[o*4]) + __popcll(s1 ^ wfp[o*4+1])
              + __popcll(s2 ^ wfp[o*4+2]) + __popcll(s3 ^ wfp[o*4+3]);
        out[n*1000 + o] = (float)(aa * (double)(256 - 2*m) + (double)bf[o]);
    }
}

extern "C" void kernel_launch(void* const* d_in, const int* in_sizes, int n_in,
                              void* d_out, int out_size, void* d_ws, size_t ws_size,
                              hipStream_t stream) {
    const float* x  = (const float*)d_in[0];
    const float* w1 = (const float*)d_in[1];
    const float* b1 = (const float*)d_in[2];
    const float* w2 = (const float*)d_in[3];
    const float* b2 = (const float*)d_in[4];
    const float* w3 = (const float*)d_in[5];
    const float* b3 = (const float*)d_in[6];
    const float* wf = (const float*)d_in[7];
    const float* bf = (const float*)d_in[8];

    char* ws = (char*)d_ws;
    uint64_t* wp2    = (uint64_t*)(ws + WP2_OFF);
    uint64_t* wp3t   = (uint64_t*)(ws + WP3T_OFF);
    uint64_t* wfp    = (uint64_t*)(ws + WFP_OFF);
    double*   part   = (double*)  (ws + PART_OFF);
    uint64_t* p1     = (uint64_t*)(ws + P1_OFF);
    uint32_t* p2     = (uint32_t*)(ws + P2_OFF);
    double*   poolp  = (double*)  (ws + POOLP_OFF);
    float*    out    = (float*)   d_out;

    hipLaunchKernelGGL(k1_conv1_pack, dim3(1056), dim3(256), 0, stream,
                       x, w1, b1, w2, w3, wf, wp2, wp3t, wfp, part, p1);
    hipLaunchKernelGGL(k2_conv2,      dim3(784),  dim3(256), 0, stream,
                       p1, b2, part, wp2, p2);
    hipLaunchKernelGGL(k3_conv3pool,  dim3(896),  dim3(256), 0, stream,
                       (const uint64_t*)p2, b3, part, wp3t, poolp);
    hipLaunchKernelGGL(k4_poolfc,     dim3(32),   dim3(256), 0, stream,
                       poolp, wfp, bf, part, out);
}